// Round 3
// baseline (500.433 us; speedup 1.0000x reference)
//
#include <hip/hip_runtime.h>
#include <hip/hip_bf16.h>

typedef float f32x4 __attribute__((ext_vector_type(4)));
typedef __bf16 bfv8 __attribute__((ext_vector_type(8)));

constexpr int Bc = 4, Sc = 2048, Ec = 1024, Hc = 16, Dc = 64;
constexpr int Mc = Bc * Sc;  // 8192 rows

__device__ __forceinline__ ushort f2bf(float f) {
  __hip_bfloat16 h = __float2bfloat16(f);
  return __builtin_bit_cast(ushort, h);
}

typedef __attribute__((address_space(1))) unsigned int as1_u32;
typedef __attribute__((address_space(3))) unsigned int as3_u32;
__device__ __forceinline__ void cp16(const ushort* g, ushort* l) {
  // async global->LDS, 16B per lane; LDS dest = wave-uniform base + lane*16
  __builtin_amdgcn_global_load_lds((as1_u32*)g, (as3_u32*)l, 16, 0, 0);
}

// ---------------- weight convert + transpose: W[K][N] f32 -> WT[N][K] bf16 ----
__global__ __launch_bounds__(256) void wcvt_kernel(const float* __restrict__ W,
                                                   ushort* __restrict__ WT,
                                                   int K, int N) {
  __shared__ float t[32][33];
  int k0 = blockIdx.x * 32, n0 = blockIdx.y * 32;
  int tx = threadIdx.x, ty = threadIdx.y;  // (32,8)
#pragma unroll
  for (int i = 0; i < 32; i += 8)
    t[ty + i][tx] = W[(size_t)(k0 + ty + i) * N + n0 + tx];
  __syncthreads();
#pragma unroll
  for (int i = 0; i < 32; i += 8)
    WT[(size_t)(n0 + ty + i) * K + k0 + tx] = f2bf(t[tx][ty + i]);
}

// ---------------- LayerNorm: row of 1024, one block per row ------------------
__global__ __launch_bounds__(256) void ln_kernel(const float* in,
                                                 const float* __restrict__ g,
                                                 const float* __restrict__ bb,
                                                 float* of, ushort* ob) {
  int row = blockIdx.x;
  int t = threadIdx.x;
  float4 x = reinterpret_cast<const float4*>(in + (size_t)row * Ec)[t];
  float s = x.x + x.y + x.z + x.w;
  float q = x.x * x.x + x.y * x.y + x.z * x.z + x.w * x.w;
#pragma unroll
  for (int o = 32; o > 0; o >>= 1) {
    s += __shfl_down(s, o);
    q += __shfl_down(q, o);
  }
  __shared__ float red[10];
  int wv = t >> 6;
  if ((t & 63) == 0) { red[wv] = s; red[4 + wv] = q; }
  __syncthreads();
  if (t == 0) {
    float S = red[0] + red[1] + red[2] + red[3];
    float Q = red[4] + red[5] + red[6] + red[7];
    float mu = S * (1.f / Ec);
    float var = Q * (1.f / Ec) - mu * mu;
    red[8] = mu;
    red[9] = rsqrtf(var + 1e-5f);
  }
  __syncthreads();
  float mu = red[8], rs = red[9];
  float4 gg = reinterpret_cast<const float4*>(g)[t];
  float4 b4 = reinterpret_cast<const float4*>(bb)[t];
  float4 y;
  y.x = (x.x - mu) * rs * gg.x + b4.x;
  y.y = (x.y - mu) * rs * gg.y + b4.y;
  y.z = (x.z - mu) * rs * gg.z + b4.z;
  y.w = (x.w - mu) * rs * gg.w + b4.w;
  reinterpret_cast<float4*>(of + (size_t)row * Ec)[t] = y;
  ushort4 u;
  u.x = f2bf(y.x); u.y = f2bf(y.y); u.z = f2bf(y.z); u.w = f2bf(y.w);
  reinterpret_cast<ushort4*>(ob + (size_t)row * Ec)[t] = u;
}

// ---------------- GEMM: C[M,N] = A[M,K](bf16) * BT[N,K]^T(bf16) + epilogue ---
// MODE 0: (acc+bias)*qscale -> bf16 [B,H,S,D] (Q,K)
// MODE 1: f32 out = acc + bias + resid (row-major)
// MODE 2: bf16 out = gelu(acc + bias) (row-major)
// MODE 3: (acc+bias) -> bf16 V^T [B,H,D,S] packed ushort4
template <int MODE>
__global__ __launch_bounds__(256) void gemm_kernel(int M, int N, int K,
                                                   const ushort* __restrict__ A,
                                                   const ushort* __restrict__ BT,
                                                   const float* __restrict__ bias,
                                                   const float* resid, float* outF,
                                                   ushort* outB, float qscale) {
  constexpr int BK = 32;
  __shared__ __align__(16) ushort As[128 * BK];
  __shared__ __align__(16) ushort Bs[128 * BK];
  const int tid = threadIdx.x;
  const int lane = tid & 63, wave = tid >> 6;
  const int wr = wave >> 1, wc = wave & 1;
  const int fr = lane & 15, fq = lane >> 4;
  // XCD-chunked swizzle: contiguous M-range per XCD (A slice + B panel fit L2)
  const int nx = gridDim.x;
  int flat = blockIdx.x + nx * blockIdx.y;
  int cpx = (nx * gridDim.y) >> 3;  // all launches have nwg % 8 == 0
  int work = (flat & 7) * cpx + (flat >> 3);
  const int n0 = (work % nx) * 128, m0 = (work / nx) * 128;

  f32x4 acc[4][4];
#pragma unroll
  for (int i = 0; i < 4; i++)
#pragma unroll
    for (int j = 0; j < 4; j++) acc[i][j] = f32x4{0.f, 0.f, 0.f, 0.f};

  const int srow = lane >> 2, schk = lane & 3;
  const ushort* Ag = A + (size_t)(m0 + wave * 32 + srow) * K + schk * 8;
  const ushort* Bg = BT + (size_t)(n0 + wave * 32 + srow) * K + schk * 8;

  for (int k0 = 0; k0 < K; k0 += BK) {
#pragma unroll
    for (int i = 0; i < 2; ++i) {
      cp16(Ag + (size_t)(i * 16) * K + k0, &As[(wave * 32 + i * 16) * BK]);
      cp16(Bg + (size_t)(i * 16) * K + k0, &Bs[(wave * 32 + i * 16) * BK]);
    }
    __syncthreads();
    bfv8 af[4], bf[4];
#pragma unroll
    for (int m = 0; m < 4; m++)
      af[m] = *reinterpret_cast<const bfv8*>(&As[(wr * 64 + m * 16 + fr) * BK + fq * 8]);
#pragma unroll
    for (int n = 0; n < 4; n++)
      bf[n] = *reinterpret_cast<const bfv8*>(&Bs[(wc * 64 + n * 16 + fr) * BK + fq * 8]);
#pragma unroll
    for (int m = 0; m < 4; m++)
#pragma unroll
      for (int n = 0; n < 4; n++)
        acc[m][n] = __builtin_amdgcn_mfma_f32_16x16x32_bf16(af[m], bf[n], acc[m][n], 0, 0, 0);
    __syncthreads();
  }

#pragma unroll
  for (int m = 0; m < 4; m++) {
#pragma unroll
    for (int n = 0; n < 4; n++) {
      const int row0 = m0 + wr * 64 + m * 16 + fq * 4;
      const int col = n0 + wc * 64 + n * 16 + fr;
      const float bb = bias[col];
      if constexpr (MODE == 3) {
        int b = row0 >> 11, sIdx = row0 & (Sc - 1);
        int h = col >> 6, d = col & (Dc - 1);
        ushort4 u;
        u.x = f2bf(acc[m][n][0] + bb);
        u.y = f2bf(acc[m][n][1] + bb);
        u.z = f2bf(acc[m][n][2] + bb);
        u.w = f2bf(acc[m][n][3] + bb);
        *reinterpret_cast<ushort4*>(
            &outB[(((size_t)b * Hc + h) * Dc + d) * Sc + sIdx]) = u;
      } else {
#pragma unroll
        for (int r = 0; r < 4; r++) {
          int row = row0 + r;
          float vacc = acc[m][n][r] + bb;
          if constexpr (MODE == 0) {
            vacc *= qscale;
            int b = row >> 11, sIdx = row & (Sc - 1);
            int h = col >> 6, d = col & (Dc - 1);
            outB[(((size_t)b * Hc + h) * Sc + sIdx) * Dc + d] = f2bf(vacc);
          } else if constexpr (MODE == 1) {
            size_t idx = (size_t)row * N + col;
            outF[idx] = vacc + resid[idx];
          } else {
            vacc = 0.5f * vacc * (1.f + erff(vacc * 0.70710678118f));
            outB[(size_t)row * N + col] = f2bf(vacc);
          }
        }
      }
    }
  }
}

// ---------------- Flash attention (QBLK=64 per wave) -------------------------
// q,k: [B,H,S,D] bf16 (q pre-scaled by log2e/sqrt(D)); vt: [B,H,D,S] bf16.
// Swapped QK^T; softmax in exp2 domain; defer-max (THR=8, log2 units).
// K/V LDS XOR-swizzled (chunk ^ row&7), staged via pre-swizzled-source
// global_load_lds; K,V fragments hoisted to registers, reused by 4 q-frags.
__global__ __launch_bounds__(256) void attn_kernel(const ushort* __restrict__ q,
                                                   const ushort* __restrict__ k,
                                                   const ushort* __restrict__ vt,
                                                   ushort* __restrict__ o) {
  int flat = blockIdx.x;                    // 512 blocks
  int swz = (flat & 7) * 64 + (flat >> 3);  // XCD-chunked
  const int qb = swz & 7;                   // 8 q-super-blocks of 256 rows
  const int bh = swz >> 3;
  const int tid = threadIdx.x, lane = tid & 63, wave = tid >> 6;
  const int fr = lane & 15, fq = lane >> 4;
  const size_t base = (size_t)bh * Sc * Dc;
  const int q0 = qb * 256 + wave * 64;

  __shared__ __align__(16) ushort Ks[64 * 64];     // [key][d], XOR-swizzled
  __shared__ __align__(16) ushort Vt[64 * 64];     // [d][key], XOR-swizzled
  __shared__ __align__(16) ushort Ps[8][16 * 72];  // ping-pong per wave

  bfv8 qf0[4], qf1[4];
#pragma unroll
  for (int f = 0; f < 4; ++f) {
    const ushort* qp = q + base + (size_t)(q0 + f * 16 + fr) * Dc + fq * 8;
    qf0[f] = *reinterpret_cast<const bfv8*>(qp);
    qf1[f] = *reinterpret_cast<const bfv8*>(qp + 32);
  }

  f32x4 oacc[4][4];  // [frag][dtile]
#pragma unroll
  for (int f = 0; f < 4; ++f)
#pragma unroll
    for (int d = 0; d < 4; ++d) oacc[f][d] = f32x4{0.f, 0.f, 0.f, 0.f};
  float mrow[4] = {-3e38f, -3e38f, -3e38f, -3e38f};
  float lrow[4] = {0.f, 0.f, 0.f, 0.f};

  const int r8 = tid >> 3;  // 0..31
  const int c8 = tid & 7;   // 16B chunk

  const int sA = (fq ^ (fr & 7)) * 8;        // swizzled read offset, chunks 0-3
  const int sB = ((fq + 4) ^ (fr & 7)) * 8;  // chunks 4-7

  for (int kt = 0; kt < Sc / 64; ++kt) {
    const int key0 = kt * 64;
#pragma unroll
    for (int i = 0; i < 2; ++i) {
      int row = i * 32 + r8;
      int sc = (c8 ^ (row & 7)) * 8;
      cp16(k + base + (size_t)(key0 + row) * Dc + sc, &Ks[i * 2048 + wave * 512]);
      cp16(vt + base + (size_t)row * Sc + key0 + sc, &Vt[i * 2048 + wave * 512]);
    }
    __syncthreads();

    bfv8 kf0[4], kf1[4], vf0[4], vf1[4];
#pragma unroll
    for (int t = 0; t < 4; ++t) {
      int e = (t * 16 + fr) * 64;
      kf0[t] = *reinterpret_cast<const bfv8*>(&Ks[e + sA]);
      kf1[t] = *reinterpret_cast<const bfv8*>(&Ks[e + sB]);
      vf0[t] = *reinterpret_cast<const bfv8*>(&Vt[e + sA]);
      vf1[t] = *reinterpret_cast<const bfv8*>(&Vt[e + sB]);
    }

#pragma unroll
    for (int f = 0; f < 4; ++f) {
      f32x4 sf[4];
#pragma unroll
      for (int t = 0; t < 4; ++t) {
        sf[t] = f32x4{0.f, 0.f, 0.f, 0.f};
        sf[t] = __builtin_amdgcn_mfma_f32_16x16x32_bf16(kf0[t], qf0[f], sf[t], 0, 0, 0);
        sf[t] = __builtin_amdgcn_mfma_f32_16x16x32_bf16(kf1[t], qf1[f], sf[t], 0, 0, 0);
      }
      // lane holds S[q=fr][key = t*16 + fq*4 + r], log2 domain
      float pmax = sf[0][0];
#pragma unroll
      for (int t = 0; t < 4; ++t)
#pragma unroll
        for (int r = 0; r < 4; ++r) pmax = fmaxf(pmax, sf[t][r]);
      float m = mrow[f];
      float mnew = m;
      if (!__all(pmax <= m + 8.f)) {
        float mt = fmaxf(pmax, __shfl_xor(pmax, 16));
        mt = fmaxf(mt, __shfl_xor(mt, 32));
        mnew = fmaxf(m, mt);
        float alpha = exp2f(m - mnew);
        float ar[4];
#pragma unroll
        for (int r = 0; r < 4; ++r) ar[r] = __shfl(alpha, fq * 4 + r);
#pragma unroll
        for (int d = 0; d < 4; ++d)
#pragma unroll
          for (int r = 0; r < 4; ++r) oacc[f][d][r] *= ar[r];
        lrow[f] *= alpha;
        mrow[f] = mnew;
      }
      float p[4][4];
      float rsum = 0.f;
#pragma unroll
      for (int t = 0; t < 4; ++t)
#pragma unroll
        for (int r = 0; r < 4; ++r) {
          p[t][r] = exp2f(sf[t][r] - mnew);
          rsum += p[t][r];
        }
      rsum += __shfl_xor(rsum, 16);
      rsum += __shfl_xor(rsum, 32);
      lrow[f] += rsum;
      ushort* pw = &Ps[wave * 2 + (f & 1)][0];
#pragma unroll
      for (int t = 0; t < 4; ++t) {
        ushort4 pu;
        pu.x = f2bf(p[t][0]);
        pu.y = f2bf(p[t][1]);
        pu.z = f2bf(p[t][2]);
        pu.w = f2bf(p[t][3]);
        *reinterpret_cast<ushort4*>(&pw[fr * 72 + t * 16 + fq * 4]) = pu;
      }
      bfv8 pf0 = *reinterpret_cast<const bfv8*>(&pw[fr * 72 + fq * 8]);
      bfv8 pf1 = *reinterpret_cast<const bfv8*>(&pw[fr * 72 + 32 + fq * 8]);
#pragma unroll
      for (int d = 0; d < 4; ++d) {
        oacc[f][d] = __builtin_amdgcn_mfma_f32_16x16x32_bf16(pf0, vf0[d], oacc[f][d], 0, 0, 0);
        oacc[f][d] = __builtin_amdgcn_mfma_f32_16x16x32_bf16(pf1, vf1[d], oacc[f][d], 0, 0, 0);
      }
    }
    __syncthreads();
  }

  const int b = bh >> 4, h = bh & 15;
#pragma unroll
  for (int f = 0; f < 4; ++f) {
    float linv[4];
#pragma unroll
    for (int r = 0; r < 4; ++r) linv[r] = 1.f / __shfl(lrow[f], fq * 4 + r);
#pragma unroll
    for (int d = 0; d < 4; ++d)
#pragma unroll
      for (int r = 0; r < 4; ++r) {
        int sIdx = q0 + f * 16 + fq * 4 + r;
        o[((size_t)(b * Sc + sIdx)) * Ec + h * 64 + d * 16 + fr] =
            f2bf(oacc[f][d][r] * linv[r]);
      }
  }
}

// -----------------------------------------------------------------------------
extern "C" void kernel_launch(void* const* d_in, const int* in_sizes, int n_in,
                              void* d_out, int out_size, void* d_ws, size_t ws_size,
                              hipStream_t stream) {
  const float* inp = (const float*)d_in[0];
  const float* ln1g = (const float*)d_in[1];
  const float* ln1b = (const float*)d_in[2];
  const float* Wq = (const float*)d_in[3];
  const float* bq = (const float*)d_in[4];
  const float* Wk = (const float*)d_in[5];
  const float* bk = (const float*)d_in[6];
  const float* Wv = (const float*)d_in[7];
  const float* bv = (const float*)d_in[8];
  const float* Wo = (const float*)d_in[9];
  const float* bo = (const float*)d_in[10];
  const float* ln2g = (const float*)d_in[11];
  const float* ln2b = (const float*)d_in[12];
  const float* W1 = (const float*)d_in[13];
  const float* b1 = (const float*)d_in[14];
  const float* W2 = (const float*)d_in[15];
  const float* b2 = (const float*)d_in[16];

  char* wsb = (char*)d_ws;
  size_t off = 0;
  auto alloc = [&](size_t bytes) {
    char* p = wsb + off;
    off += (bytes + 255) & ~(size_t)255;
    return p;
  };
  float* xf = (float*)alloc((size_t)Mc * Ec * 4);
  ushort* xb = (ushort*)alloc((size_t)Mc * Ec * 2);
  ushort* qbuf = (ushort*)alloc((size_t)Mc * Ec * 2);
  ushort* kbuf = (ushort*)alloc((size_t)Mc * Ec * 2);
  ushort* vtbuf = (ushort*)alloc((size_t)Mc * Ec * 2);
  ushort* abuf = (ushort*)alloc((size_t)Mc * Ec * 2);
  ushort* h1 = (ushort*)alloc((size_t)Mc * 2 * Ec * 2);
  ushort* WqT = (ushort*)alloc((size_t)Ec * Ec * 2);
  ushort* WkT = (ushort*)alloc((size_t)Ec * Ec * 2);
  ushort* WvT = (ushort*)alloc((size_t)Ec * Ec * 2);
  ushort* WoT = (ushort*)alloc((size_t)Ec * Ec * 2);
  ushort* W1T = (ushort*)alloc((size_t)Ec * 2 * Ec * 2);
  ushort* W2T = (ushort*)alloc((size_t)Ec * 2 * Ec * 2);
  (void)in_sizes; (void)n_in; (void)out_size; (void)ws_size;

  dim3 tb(32, 8);
  wcvt_kernel<<<dim3(Ec / 32, Ec / 32), tb, 0, stream>>>(Wq, WqT, Ec, Ec);
  wcvt_kernel<<<dim3(Ec / 32, Ec / 32), tb, 0, stream>>>(Wk, WkT, Ec, Ec);
  wcvt_kernel<<<dim3(Ec / 32, Ec / 32), tb, 0, stream>>>(Wv, WvT, Ec, Ec);
  wcvt_kernel<<<dim3(Ec / 32, Ec / 32), tb, 0, stream>>>(Wo, WoT, Ec, Ec);
  wcvt_kernel<<<dim3(Ec / 32, 2 * Ec / 32), tb, 0, stream>>>(W1, W1T, Ec, 2 * Ec);
  wcvt_kernel<<<dim3(2 * Ec / 32, Ec / 32), tb, 0, stream>>>(W2, W2T, 2 * Ec, Ec);

  ln_kernel<<<Mc, 256, 0, stream>>>(inp, ln1g, ln1b, xf, xb);

  // Q pre-scale: (1/sqrt(D)) * log2(e) -> softmax computed in exp2 domain
  gemm_kernel<0><<<dim3(Ec / 128, Mc / 128), 256, 0, stream>>>(
      Mc, Ec, Ec, xb, WqT, bq, nullptr, nullptr, qbuf, 0.18033688f);
  gemm_kernel<0><<<dim3(Ec / 128, Mc / 128), 256, 0, stream>>>(
      Mc, Ec, Ec, xb, WkT, bk, nullptr, nullptr, kbuf, 1.f);
  gemm_kernel<3><<<dim3(Ec / 128, Mc / 128), 256, 0, stream>>>(
      Mc, Ec, Ec, xb, WvT, bv, nullptr, nullptr, vtbuf, 1.f);

  attn_kernel<<<Bc * Hc * (Sc / 256), 256, 0, stream>>>(qbuf, kbuf, vtbuf, abuf);

  gemm_kernel<1><<<dim3(Ec / 128, Mc / 128), 256, 0, stream>>>(
      Mc, Ec, Ec, abuf, WoT, bo, xf, xf, nullptr, 1.f);

  ln_kernel<<<Mc, 256, 0, stream>>>(xf, ln2g, ln2b, xf, xb);

  gemm_kernel<2><<<dim3(2 * Ec / 128, Mc / 128), 256, 0, stream>>>(
      Mc, 2 * Ec, Ec, xb, W1T, b1, nullptr, nullptr, h1, 1.f);

  gemm_kernel<1><<<dim3(Ec / 128, Mc / 128), 256, 0, stream>>>(
      Mc, Ec, 2 * Ec, h1, W2T, b2, xf, (float*)d_out, nullptr, 1.f);
}

// Round 4
// 445.978 us; speedup vs baseline: 1.1221x; 1.1221x over previous
//
#include <hip/hip_runtime.h>
#include <hip/hip_bf16.h>

typedef float f32x4 __attribute__((ext_vector_type(4)));
typedef __bf16 bfv8 __attribute__((ext_vector_type(8)));

constexpr int Bc = 4, Sc = 2048, Ec = 1024, Hc = 16, Dc = 64;
constexpr int Mc = Bc * Sc;  // 8192 rows

__device__ __forceinline__ ushort f2bf(float f) {
  __hip_bfloat16 h = __float2bfloat16(f);
  return __builtin_bit_cast(ushort, h);
}

typedef __attribute__((address_space(1))) unsigned int as1_u32;
typedef __attribute__((address_space(3))) unsigned int as3_u32;
__device__ __forceinline__ void cp16(const ushort* g, ushort* l) {
  // async global->LDS, 16B per lane; LDS dest = wave-uniform base + lane*16
  __builtin_amdgcn_global_load_lds((as1_u32*)g, (as3_u32*)l, 16, 0, 0);
}

// ---------------- weight convert + transpose: W[K][N] f32 -> WT[N][K] bf16 ----
__global__ __launch_bounds__(256) void wcvt_kernel(const float* __restrict__ W,
                                                   ushort* __restrict__ WT,
                                                   int K, int N) {
  __shared__ float t[32][33];
  int k0 = blockIdx.x * 32, n0 = blockIdx.y * 32;
  int tx = threadIdx.x, ty = threadIdx.y;  // (32,8)
#pragma unroll
  for (int i = 0; i < 32; i += 8)
    t[ty + i][tx] = W[(size_t)(k0 + ty + i) * N + n0 + tx];
  __syncthreads();
#pragma unroll
  for (int i = 0; i < 32; i += 8)
    WT[(size_t)(n0 + ty + i) * K + k0 + tx] = f2bf(t[tx][ty + i]);
}

// ---------------- LayerNorm: row of 1024, one block per row ------------------
__global__ __launch_bounds__(256) void ln_kernel(const float* in,
                                                 const float* __restrict__ g,
                                                 const float* __restrict__ bb,
                                                 float* of, ushort* ob) {
  int row = blockIdx.x;
  int t = threadIdx.x;
  float4 x = reinterpret_cast<const float4*>(in + (size_t)row * Ec)[t];
  float s = x.x + x.y + x.z + x.w;
  float q = x.x * x.x + x.y * x.y + x.z * x.z + x.w * x.w;
#pragma unroll
  for (int o = 32; o > 0; o >>= 1) {
    s += __shfl_down(s, o);
    q += __shfl_down(q, o);
  }
  __shared__ float red[10];
  int wv = t >> 6;
  if ((t & 63) == 0) { red[wv] = s; red[4 + wv] = q; }
  __syncthreads();
  if (t == 0) {
    float S = red[0] + red[1] + red[2] + red[3];
    float Q = red[4] + red[5] + red[6] + red[7];
    float mu = S * (1.f / Ec);
    float var = Q * (1.f / Ec) - mu * mu;
    red[8] = mu;
    red[9] = rsqrtf(var + 1e-5f);
  }
  __syncthreads();
  float mu = red[8], rs = red[9];
  float4 gg = reinterpret_cast<const float4*>(g)[t];
  float4 b4 = reinterpret_cast<const float4*>(bb)[t];
  float4 y;
  y.x = (x.x - mu) * rs * gg.x + b4.x;
  y.y = (x.y - mu) * rs * gg.y + b4.y;
  y.z = (x.z - mu) * rs * gg.z + b4.z;
  y.w = (x.w - mu) * rs * gg.w + b4.w;
  reinterpret_cast<float4*>(of + (size_t)row * Ec)[t] = y;
  ushort4 u;
  u.x = f2bf(y.x); u.y = f2bf(y.y); u.z = f2bf(y.z); u.w = f2bf(y.w);
  reinterpret_cast<ushort4*>(ob + (size_t)row * Ec)[t] = u;
}

// ---------------- GEMM: C[M,N] = A[M,K](bf16) * BT[N,K]^T(bf16) + epilogue ---
// MODE 0: (acc+bias)*qscale -> bf16 [B,H,S,D] (Q,K)
// MODE 1: f32 out = acc + bias + resid (row-major)
// MODE 2: bf16 out = gelu(acc + bias) (row-major)
// MODE 3: (acc+bias) -> bf16 V^T [B,H,D,S] packed ushort4
template <int MODE>
__global__ __launch_bounds__(256) void gemm_kernel(int M, int N, int K,
                                                   const ushort* __restrict__ A,
                                                   const ushort* __restrict__ BT,
                                                   const float* __restrict__ bias,
                                                   const float* resid, float* outF,
                                                   ushort* outB, float qscale) {
  constexpr int BK = 32;
  __shared__ __align__(16) ushort As[128 * BK];
  __shared__ __align__(16) ushort Bs[128 * BK];
  const int tid = threadIdx.x;
  const int lane = tid & 63, wave = tid >> 6;
  const int wr = wave >> 1, wc = wave & 1;
  const int fr = lane & 15, fq = lane >> 4;
  // XCD-chunked swizzle: contiguous M-range per XCD (A slice + B panel fit L2)
  const int nx = gridDim.x;
  int flat = blockIdx.x + nx * blockIdx.y;
  int cpx = (nx * gridDim.y) >> 3;  // all launches have nwg % 8 == 0
  int work = (flat & 7) * cpx + (flat >> 3);
  const int n0 = (work % nx) * 128, m0 = (work / nx) * 128;

  f32x4 acc[4][4];
#pragma unroll
  for (int i = 0; i < 4; i++)
#pragma unroll
    for (int j = 0; j < 4; j++) acc[i][j] = f32x4{0.f, 0.f, 0.f, 0.f};

  const int srow = lane >> 2, schk = lane & 3;
  const ushort* Ag = A + (size_t)(m0 + wave * 32 + srow) * K + schk * 8;
  const ushort* Bg = BT + (size_t)(n0 + wave * 32 + srow) * K + schk * 8;

  for (int k0 = 0; k0 < K; k0 += BK) {
#pragma unroll
    for (int i = 0; i < 2; ++i) {
      cp16(Ag + (size_t)(i * 16) * K + k0, &As[(wave * 32 + i * 16) * BK]);
      cp16(Bg + (size_t)(i * 16) * K + k0, &Bs[(wave * 32 + i * 16) * BK]);
    }
    __syncthreads();
    bfv8 af[4], bf[4];
#pragma unroll
    for (int m = 0; m < 4; m++)
      af[m] = *reinterpret_cast<const bfv8*>(&As[(wr * 64 + m * 16 + fr) * BK + fq * 8]);
#pragma unroll
    for (int n = 0; n < 4; n++)
      bf[n] = *reinterpret_cast<const bfv8*>(&Bs[(wc * 64 + n * 16 + fr) * BK + fq * 8]);
    __builtin_amdgcn_s_setprio(1);
#pragma unroll
    for (int m = 0; m < 4; m++)
#pragma unroll
      for (int n = 0; n < 4; n++)
        acc[m][n] = __builtin_amdgcn_mfma_f32_16x16x32_bf16(af[m], bf[n], acc[m][n], 0, 0, 0);
    __builtin_amdgcn_s_setprio(0);
    __syncthreads();
  }

#pragma unroll
  for (int m = 0; m < 4; m++) {
#pragma unroll
    for (int n = 0; n < 4; n++) {
      const int row0 = m0 + wr * 64 + m * 16 + fq * 4;
      const int col = n0 + wc * 64 + n * 16 + fr;
      const float bb = bias[col];
      if constexpr (MODE == 3) {
        int b = row0 >> 11, sIdx = row0 & (Sc - 1);
        int h = col >> 6, d = col & (Dc - 1);
        ushort4 u;
        u.x = f2bf(acc[m][n][0] + bb);
        u.y = f2bf(acc[m][n][1] + bb);
        u.z = f2bf(acc[m][n][2] + bb);
        u.w = f2bf(acc[m][n][3] + bb);
        *reinterpret_cast<ushort4*>(
            &outB[(((size_t)b * Hc + h) * Dc + d) * Sc + sIdx]) = u;
      } else {
#pragma unroll
        for (int r = 0; r < 4; r++) {
          int row = row0 + r;
          float vacc = acc[m][n][r] + bb;
          if constexpr (MODE == 0) {
            vacc *= qscale;
            int b = row >> 11, sIdx = row & (Sc - 1);
            int h = col >> 6, d = col & (Dc - 1);
            outB[(((size_t)b * Hc + h) * Sc + sIdx) * Dc + d] = f2bf(vacc);
          } else if constexpr (MODE == 1) {
            size_t idx = (size_t)row * N + col;
            outF[idx] = vacc + resid[idx];
          } else {
            vacc = 0.5f * vacc * (1.f + erff(vacc * 0.70710678118f));
            outB[(size_t)row * N + col] = f2bf(vacc);
          }
        }
      }
    }
  }
}

// ---------------- Flash attention (32 q-rows per wave, 128 per block) --------
// q,k: [B,H,S,D] bf16 (q pre-scaled by log2e/sqrt(D)); vt: [B,H,D,S] bf16.
// Swapped QK^T; softmax in exp2 domain; defer-max (THR=8, log2 units).
// K/V LDS XOR-swizzled, staged via pre-swizzled-source global_load_lds;
// K,V fragments hoisted to registers, reused by 2 q-frags.
__global__ __launch_bounds__(256) void attn_kernel(const ushort* __restrict__ q,
                                                   const ushort* __restrict__ k,
                                                   const ushort* __restrict__ vt,
                                                   ushort* __restrict__ o) {
  int flat = blockIdx.x;                     // 1024 blocks
  int swz = (flat & 7) * 128 + (flat >> 3);  // XCD-chunked: 8 heads per XCD
  const int qb = swz & 15;                   // 16 q-blocks of 128 rows
  const int bh = swz >> 4;
  const int tid = threadIdx.x, lane = tid & 63, wave = tid >> 6;
  const int fr = lane & 15, fq = lane >> 4;
  const size_t base = (size_t)bh * Sc * Dc;
  const int q0 = qb * 128 + wave * 32;

  __shared__ __align__(16) ushort Ks[64 * 64];     // [key][d], XOR-swizzled
  __shared__ __align__(16) ushort Vt[64 * 64];     // [d][key], XOR-swizzled
  __shared__ __align__(16) ushort Ps[8][16 * 72];  // ping-pong per wave

  bfv8 qf0[2], qf1[2];
#pragma unroll
  for (int f = 0; f < 2; ++f) {
    const ushort* qp = q + base + (size_t)(q0 + f * 16 + fr) * Dc + fq * 8;
    qf0[f] = *reinterpret_cast<const bfv8*>(qp);
    qf1[f] = *reinterpret_cast<const bfv8*>(qp + 32);
  }

  f32x4 oacc[2][4];  // [frag][dtile]
#pragma unroll
  for (int f = 0; f < 2; ++f)
#pragma unroll
    for (int d = 0; d < 4; ++d) oacc[f][d] = f32x4{0.f, 0.f, 0.f, 0.f};
  float mrow[2] = {-3e38f, -3e38f};
  float lrow[2] = {0.f, 0.f};

  const int r8 = tid >> 3;  // 0..31
  const int c8 = tid & 7;   // 16B chunk

  const int sA = (fq ^ (fr & 7)) * 8;        // swizzled read offset, chunks 0-3
  const int sB = ((fq + 4) ^ (fr & 7)) * 8;  // chunks 4-7

  for (int kt = 0; kt < Sc / 64; ++kt) {
    const int key0 = kt * 64;
#pragma unroll
    for (int i = 0; i < 2; ++i) {
      int row = i * 32 + r8;
      int sc = (c8 ^ (row & 7)) * 8;
      cp16(k + base + (size_t)(key0 + row) * Dc + sc, &Ks[i * 2048 + wave * 512]);
      cp16(vt + base + (size_t)row * Sc + key0 + sc, &Vt[i * 2048 + wave * 512]);
    }
    __syncthreads();

    bfv8 kf0[4], kf1[4], vf0[4], vf1[4];
#pragma unroll
    for (int t = 0; t < 4; ++t) {
      int e = (t * 16 + fr) * 64;
      kf0[t] = *reinterpret_cast<const bfv8*>(&Ks[e + sA]);
      kf1[t] = *reinterpret_cast<const bfv8*>(&Ks[e + sB]);
      vf0[t] = *reinterpret_cast<const bfv8*>(&Vt[e + sA]);
      vf1[t] = *reinterpret_cast<const bfv8*>(&Vt[e + sB]);
    }

#pragma unroll
    for (int f = 0; f < 2; ++f) {
      f32x4 sf[4];
      __builtin_amdgcn_s_setprio(1);
#pragma unroll
      for (int t = 0; t < 4; ++t) {
        sf[t] = f32x4{0.f, 0.f, 0.f, 0.f};
        sf[t] = __builtin_amdgcn_mfma_f32_16x16x32_bf16(kf0[t], qf0[f], sf[t], 0, 0, 0);
        sf[t] = __builtin_amdgcn_mfma_f32_16x16x32_bf16(kf1[t], qf1[f], sf[t], 0, 0, 0);
      }
      __builtin_amdgcn_s_setprio(0);
      // lane holds S[q=fr][key = t*16 + fq*4 + r], log2 domain
      float pmax = sf[0][0];
#pragma unroll
      for (int t = 0; t < 4; ++t)
#pragma unroll
        for (int r = 0; r < 4; ++r) pmax = fmaxf(pmax, sf[t][r]);
      float m = mrow[f];
      float mnew = m;
      if (!__all(pmax <= m + 8.f)) {
        float mt = fmaxf(pmax, __shfl_xor(pmax, 16));
        mt = fmaxf(mt, __shfl_xor(mt, 32));
        mnew = fmaxf(m, mt);
        float alpha = exp2f(m - mnew);
        float ar[4];
#pragma unroll
        for (int r = 0; r < 4; ++r) ar[r] = __shfl(alpha, fq * 4 + r);
#pragma unroll
        for (int d = 0; d < 4; ++d)
#pragma unroll
          for (int r = 0; r < 4; ++r) oacc[f][d][r] *= ar[r];
        lrow[f] *= alpha;
        mrow[f] = mnew;
      }
      float p[4][4];
      float rsum = 0.f;
#pragma unroll
      for (int t = 0; t < 4; ++t)
#pragma unroll
        for (int r = 0; r < 4; ++r) {
          p[t][r] = exp2f(sf[t][r] - mnew);
          rsum += p[t][r];
        }
      rsum += __shfl_xor(rsum, 16);
      rsum += __shfl_xor(rsum, 32);
      lrow[f] += rsum;
      ushort* pw = &Ps[wave * 2 + (f & 1)][0];
#pragma unroll
      for (int t = 0; t < 4; ++t) {
        ushort4 pu;
        pu.x = f2bf(p[t][0]);
        pu.y = f2bf(p[t][1]);
        pu.z = f2bf(p[t][2]);
        pu.w = f2bf(p[t][3]);
        *reinterpret_cast<ushort4*>(&pw[fr * 72 + t * 16 + fq * 4]) = pu;
      }
      bfv8 pf0 = *reinterpret_cast<const bfv8*>(&pw[fr * 72 + fq * 8]);
      bfv8 pf1 = *reinterpret_cast<const bfv8*>(&pw[fr * 72 + 32 + fq * 8]);
      __builtin_amdgcn_s_setprio(1);
#pragma unroll
      for (int d = 0; d < 4; ++d) {
        oacc[f][d] = __builtin_amdgcn_mfma_f32_16x16x32_bf16(pf0, vf0[d], oacc[f][d], 0, 0, 0);
        oacc[f][d] = __builtin_amdgcn_mfma_f32_16x16x32_bf16(pf1, vf1[d], oacc[f][d], 0, 0, 0);
      }
      __builtin_amdgcn_s_setprio(0);
    }
    __syncthreads();
  }

  const int b = bh >> 4, h = bh & 15;
#pragma unroll
  for (int f = 0; f < 2; ++f) {
    float linv[4];
#pragma unroll
    for (int r = 0; r < 4; ++r) linv[r] = 1.f / __shfl(lrow[f], fq * 4 + r);
#pragma unroll
    for (int d = 0; d < 4; ++d)
#pragma unroll
      for (int r = 0; r < 4; ++r) {
        int sIdx = q0 + f * 16 + fq * 4 + r;
        o[((size_t)(b * Sc + sIdx)) * Ec + h * 64 + d * 16 + fr] =
            f2bf(oacc[f][d][r] * linv[r]);
      }
  }
}

// -----------------------------------------------------------------------------
extern "C" void kernel_launch(void* const* d_in, const int* in_sizes, int n_in,
                              void* d_out, int out_size, void* d_ws, size_t ws_size,
                              hipStream_t stream) {
  const float* inp = (const float*)d_in[0];
  const float* ln1g = (const float*)d_in[1];
  const float* ln1b = (const float*)d_in[2];
  const float* Wq = (const float*)d_in[3];
  const float* bq = (const float*)d_in[4];
  const float* Wk = (const float*)d_in[5];
  const float* bk = (const float*)d_in[6];
  const float* Wv = (const float*)d_in[7];
  const float* bv = (const float*)d_in[8];
  const float* Wo = (const float*)d_in[9];
  const float* bo = (const float*)d_in[10];
  const float* ln2g = (const float*)d_in[11];
  const float* ln2b = (const float*)d_in[12];
  const float* W1 = (const float*)d_in[13];
  const float* b1 = (const float*)d_in[14];
  const float* W2 = (const float*)d_in[15];
  const float* b2 = (const float*)d_in[16];

  char* wsb = (char*)d_ws;
  size_t off = 0;
  auto alloc = [&](size_t bytes) {
    char* p = wsb + off;
    off += (bytes + 255) & ~(size_t)255;
    return p;
  };
  float* xf = (float*)alloc((size_t)Mc * Ec * 4);
  ushort* xb = (ushort*)alloc((size_t)Mc * Ec * 2);
  ushort* qbuf = (ushort*)alloc((size_t)Mc * Ec * 2);
  ushort* kbuf = (ushort*)alloc((size_t)Mc * Ec * 2);
  ushort* vtbuf = (ushort*)alloc((size_t)Mc * Ec * 2);
  ushort* abuf = (ushort*)alloc((size_t)Mc * Ec * 2);
  ushort* h1 = (ushort*)alloc((size_t)Mc * 2 * Ec * 2);
  ushort* WqT = (ushort*)alloc((size_t)Ec * Ec * 2);
  ushort* WkT = (ushort*)alloc((size_t)Ec * Ec * 2);
  ushort* WvT = (ushort*)alloc((size_t)Ec * Ec * 2);
  ushort* WoT = (ushort*)alloc((size_t)Ec * Ec * 2);
  ushort* W1T = (ushort*)alloc((size_t)Ec * 2 * Ec * 2);
  ushort* W2T = (ushort*)alloc((size_t)Ec * 2 * Ec * 2);
  (void)in_sizes; (void)n_in; (void)out_size; (void)ws_size;

  dim3 tb(32, 8);
  wcvt_kernel<<<dim3(Ec / 32, Ec / 32), tb, 0, stream>>>(Wq, WqT, Ec, Ec);
  wcvt_kernel<<<dim3(Ec / 32, Ec / 32), tb, 0, stream>>>(Wk, WkT, Ec, Ec);
  wcvt_kernel<<<dim3(Ec / 32, Ec / 32), tb, 0, stream>>>(Wv, WvT, Ec, Ec);
  wcvt_kernel<<<dim3(Ec / 32, Ec / 32), tb, 0, stream>>>(Wo, WoT, Ec, Ec);
  wcvt_kernel<<<dim3(Ec / 32, 2 * Ec / 32), tb, 0, stream>>>(W1, W1T, Ec, 2 * Ec);
  wcvt_kernel<<<dim3(2 * Ec / 32, Ec / 32), tb, 0, stream>>>(W2, W2T, 2 * Ec, Ec);

  ln_kernel<<<Mc, 256, 0, stream>>>(inp, ln1g, ln1b, xf, xb);

  // Q pre-scale: (1/sqrt(D)) * log2(e) -> softmax computed in exp2 domain
  gemm_kernel<0><<<dim3(Ec / 128, Mc / 128), 256, 0, stream>>>(
      Mc, Ec, Ec, xb, WqT, bq, nullptr, nullptr, qbuf, 0.18033688f);
  gemm_kernel<0><<<dim3(Ec / 128, Mc / 128), 256, 0, stream>>>(
      Mc, Ec, Ec, xb, WkT, bk, nullptr, nullptr, kbuf, 1.f);
  gemm_kernel<3><<<dim3(Ec / 128, Mc / 128), 256, 0, stream>>>(
      Mc, Ec, Ec, xb, WvT, bv, nullptr, nullptr, vtbuf, 1.f);

  attn_kernel<<<Bc * Hc * (Sc / 128), 256, 0, stream>>>(qbuf, kbuf, vtbuf, abuf);

  gemm_kernel<1><<<dim3(Ec / 128, Mc / 128), 256, 0, stream>>>(
      Mc, Ec, Ec, abuf, WoT, bo, xf, xf, nullptr, 1.f);

  ln_kernel<<<Mc, 256, 0, stream>>>(xf, ln2g, ln2b, xf, xb);

  gemm_kernel<2><<<dim3(2 * Ec / 128, Mc / 128), 256, 0, stream>>>(
      Mc, 2 * Ec, Ec, xb, W1T, b1, nullptr, nullptr, h1, 1.f);

  gemm_kernel<1><<<dim3(Ec / 128, Mc / 128), 256, 0, stream>>>(
      Mc, Ec, 2 * Ec, h1, W2T, b2, xf, (float*)d_out, nullptr, 1.f);
}

// Round 5
// 416.770 us; speedup vs baseline: 1.2007x; 1.0701x over previous
//
#include <hip/hip_runtime.h>
#include <hip/hip_bf16.h>

typedef float f32x4 __attribute__((ext_vector_type(4)));
typedef __bf16 bfv8 __attribute__((ext_vector_type(8)));

constexpr int Bc = 4, Sc = 2048, Ec = 1024, Hc = 16, Dc = 64;
constexpr int Mc = Bc * Sc;  // 8192 rows

__device__ __forceinline__ ushort f2bf(float f) {
  __hip_bfloat16 h = __float2bfloat16(f);
  return __builtin_bit_cast(ushort, h);
}

typedef __attribute__((address_space(1))) unsigned int as1_u32;
typedef __attribute__((address_space(3))) unsigned int as3_u32;
__device__ __forceinline__ void cp16(const ushort* g, ushort* l) {
  // async global->LDS, 16B per lane; LDS dest = wave-uniform base + lane*16
  __builtin_amdgcn_global_load_lds((as1_u32*)g, (as3_u32*)l, 16, 0, 0);
}

// ---------------- weight convert + transpose: W[K][N] f32 -> WT[N][K] bf16 ----
__global__ __launch_bounds__(256) void wcvt_kernel(const float* __restrict__ W,
                                                   ushort* __restrict__ WT,
                                                   int K, int N) {
  __shared__ float t[32][33];
  int k0 = blockIdx.x * 32, n0 = blockIdx.y * 32;
  int tx = threadIdx.x, ty = threadIdx.y;  // (32,8)
#pragma unroll
  for (int i = 0; i < 32; i += 8)
    t[ty + i][tx] = W[(size_t)(k0 + ty + i) * N + n0 + tx];
  __syncthreads();
#pragma unroll
  for (int i = 0; i < 32; i += 8)
    WT[(size_t)(n0 + ty + i) * K + k0 + tx] = f2bf(t[tx][ty + i]);
}

// ---------------- LayerNorm: row of 1024, one block per row ------------------
__global__ __launch_bounds__(256) void ln_kernel(const float* in,
                                                 const float* __restrict__ g,
                                                 const float* __restrict__ bb,
                                                 float* of, ushort* ob) {
  int row = blockIdx.x;
  int t = threadIdx.x;
  float4 x = reinterpret_cast<const float4*>(in + (size_t)row * Ec)[t];
  float s = x.x + x.y + x.z + x.w;
  float q = x.x * x.x + x.y * x.y + x.z * x.z + x.w * x.w;
#pragma unroll
  for (int o = 32; o > 0; o >>= 1) {
    s += __shfl_down(s, o);
    q += __shfl_down(q, o);
  }
  __shared__ float red[10];
  int wv = t >> 6;
  if ((t & 63) == 0) { red[wv] = s; red[4 + wv] = q; }
  __syncthreads();
  if (t == 0) {
    float S = red[0] + red[1] + red[2] + red[3];
    float Q = red[4] + red[5] + red[6] + red[7];
    float mu = S * (1.f / Ec);
    float var = Q * (1.f / Ec) - mu * mu;
    red[8] = mu;
    red[9] = rsqrtf(var + 1e-5f);
  }
  __syncthreads();
  float mu = red[8], rs = red[9];
  float4 gg = reinterpret_cast<const float4*>(g)[t];
  float4 b4 = reinterpret_cast<const float4*>(bb)[t];
  float4 y;
  y.x = (x.x - mu) * rs * gg.x + b4.x;
  y.y = (x.y - mu) * rs * gg.y + b4.y;
  y.z = (x.z - mu) * rs * gg.z + b4.z;
  y.w = (x.w - mu) * rs * gg.w + b4.w;
  reinterpret_cast<float4*>(of + (size_t)row * Ec)[t] = y;
  ushort4 u;
  u.x = f2bf(y.x); u.y = f2bf(y.y); u.z = f2bf(y.z); u.w = f2bf(y.w);
  reinterpret_cast<ushort4*>(ob + (size_t)row * Ec)[t] = u;
}

// ---------------- GEMM: C[M,N] = A[M,K](bf16) * BT[N,K]^T(bf16) + epilogue ---
// 128x128 tile, BK=64, LDS double-buffered (64KB, 2 blocks/CU), counted
// vmcnt(8) + raw s_barrier so next tile's global_load_lds stays in flight
// across the barrier. LDS XOR-swizzled (col ^= (row&3)<<4) via pre-swizzled
// global source; frag ds_read_b128 at the 8-cy wave64 floor.
// MODE 0: fused QKV, N=3Ec; region 0 -> Q*qscale [B,H,S,D], 1 -> K [B,H,S,D],
//         2 -> V^T [B,H,D,S] packed ushort4
// MODE 1: f32 out = acc + bias + resid (row-major)
// MODE 2: bf16 out = gelu(acc + bias) (row-major)
template <int MODE>
__global__ __launch_bounds__(256, 2) void gemm_kernel(
    int M, int N, int K, const ushort* __restrict__ A,
    const ushort* __restrict__ BT, const float* __restrict__ b0,
    const float* __restrict__ b1, const float* __restrict__ b2,
    const float* resid, float* outF, ushort* o0, ushort* o1, ushort* o2,
    float qscale) {
  __shared__ __align__(16) ushort As[2][128 * 64];
  __shared__ __align__(16) ushort Bs[2][128 * 64];
  const int tid = threadIdx.x;
  const int lane = tid & 63, wave = tid >> 6;
  const int wr = wave >> 1, wc = wave & 1;
  const int fr = lane & 15, fq = lane >> 4;
  // XCD-chunked swizzle (nwg % 8 == 0 for all launches)
  const int nx = gridDim.x;
  int flat = blockIdx.x + nx * blockIdx.y;
  int cpx = (nx * gridDim.y) >> 3;
  int work = (flat & 7) * cpx + (flat >> 3);
  const int n0 = (work % nx) * 128, m0 = (work / nx) * 128;

  f32x4 acc[4][4];
#pragma unroll
  for (int i = 0; i < 4; i++)
#pragma unroll
    for (int j = 0; j < 4; j++) acc[i][j] = f32x4{0.f, 0.f, 0.f, 0.f};

  const int srow = tid >> 3;   // 0..31 (+32 per chunk)
  const int sslot = tid & 7;   // 16B slot within 128B row

  auto STAGE = [&](int p, int k0) {
#pragma unroll
    for (int c = 0; c < 4; ++c) {
      int row = c * 32 + srow;
      int scol = (sslot ^ (2 * (row & 3))) * 8;  // inverse-swizzled source
      cp16(A + (size_t)(m0 + row) * K + k0 + scol,
           &As[p][(c * 256 + wave * 64) * 8]);
      cp16(BT + (size_t)(n0 + row) * K + k0 + scol,
           &Bs[p][(c * 256 + wave * 64) * 8]);
    }
  };

  STAGE(0, 0);
  const int nt = K >> 6;
  for (int kt = 0; kt < nt; ++kt) {
    const int p = kt & 1;
    if (kt + 1 < nt) {
      STAGE(p ^ 1, (kt + 1) << 6);
      asm volatile("s_waitcnt vmcnt(8)" ::: "memory");  // tile kt landed
    } else {
      asm volatile("s_waitcnt vmcnt(0)" ::: "memory");
    }
    __builtin_amdgcn_s_barrier();
#pragma unroll
    for (int kk = 0; kk < 2; ++kk) {
      bfv8 af[4], bf[4];
#pragma unroll
      for (int m = 0; m < 4; m++) {
        int row = wr * 64 + m * 16 + fr;
        af[m] = *reinterpret_cast<const bfv8*>(
            &As[p][row * 64 + ((kk * 32 + fq * 8) ^ ((fr & 3) << 4))]);
      }
#pragma unroll
      for (int n = 0; n < 4; n++) {
        int row = wc * 64 + n * 16 + fr;
        bf[n] = *reinterpret_cast<const bfv8*>(
            &Bs[p][row * 64 + ((kk * 32 + fq * 8) ^ ((fr & 3) << 4))]);
      }
      __builtin_amdgcn_s_setprio(1);
#pragma unroll
      for (int m = 0; m < 4; m++)
#pragma unroll
        for (int n = 0; n < 4; n++)
          acc[m][n] =
              __builtin_amdgcn_mfma_f32_16x16x32_bf16(af[m], bf[n], acc[m][n], 0, 0, 0);
      __builtin_amdgcn_s_setprio(0);
    }
    __builtin_amdgcn_sched_barrier(0);
    __builtin_amdgcn_s_barrier();
  }

#pragma unroll
  for (int m = 0; m < 4; m++) {
#pragma unroll
    for (int n = 0; n < 4; n++) {
      const int row0 = m0 + wr * 64 + m * 16 + fq * 4;
      const int col = n0 + wc * 64 + n * 16 + fr;
      if constexpr (MODE == 0) {
        const int region = col >> 10, c1 = col & (Ec - 1);
        const int b = row0 >> 11, s0 = row0 & (Sc - 1);
        const int h = c1 >> 6, d = c1 & (Dc - 1);
        const float bb = (region == 0 ? b0 : region == 1 ? b1 : b2)[c1];
        if (region == 2) {
          ushort4 u;
          u.x = f2bf(acc[m][n][0] + bb);
          u.y = f2bf(acc[m][n][1] + bb);
          u.z = f2bf(acc[m][n][2] + bb);
          u.w = f2bf(acc[m][n][3] + bb);
          *reinterpret_cast<ushort4*>(
              &o2[(((size_t)b * Hc + h) * Dc + d) * Sc + s0]) = u;
        } else {
          ushort* dst = region ? o1 : o0;
          const float sc = region ? 1.f : qscale;
#pragma unroll
          for (int r = 0; r < 4; r++)
            dst[(((size_t)b * Hc + h) * Sc + s0 + r) * Dc + d] =
                f2bf((acc[m][n][r] + bb) * sc);
        }
      } else {
        const float bb = b0[col];
#pragma unroll
        for (int r = 0; r < 4; r++) {
          int row = row0 + r;
          float vacc = acc[m][n][r] + bb;
          if constexpr (MODE == 1) {
            size_t idx = (size_t)row * N + col;
            outF[idx] = vacc + resid[idx];
          } else {
            vacc = 0.5f * vacc * (1.f + erff(vacc * 0.70710678118f));
            o0[(size_t)row * N + col] = f2bf(vacc);
          }
        }
      }
    }
  }
}

// ---------------- Flash attention (32 q-rows per wave, 128 per block) --------
// q,k: [B,H,S,D] bf16 (q pre-scaled by log2e/sqrt(D)); vt: [B,H,D,S] bf16.
// Swapped QK^T; softmax in exp2 domain; defer-max (THR=8, log2 units).
// K/V LDS XOR-swizzled, staged via pre-swizzled-source global_load_lds;
// K,V fragments hoisted to registers, reused by 2 q-frags.
__global__ __launch_bounds__(256) void attn_kernel(const ushort* __restrict__ q,
                                                   const ushort* __restrict__ k,
                                                   const ushort* __restrict__ vt,
                                                   ushort* __restrict__ o) {
  int flat = blockIdx.x;                     // 1024 blocks
  int swz = (flat & 7) * 128 + (flat >> 3);  // XCD-chunked: 8 heads per XCD
  const int qb = swz & 15;                   // 16 q-blocks of 128 rows
  const int bh = swz >> 4;
  const int tid = threadIdx.x, lane = tid & 63, wave = tid >> 6;
  const int fr = lane & 15, fq = lane >> 4;
  const size_t base = (size_t)bh * Sc * Dc;
  const int q0 = qb * 128 + wave * 32;

  __shared__ __align__(16) ushort Ks[64 * 64];     // [key][d], XOR-swizzled
  __shared__ __align__(16) ushort Vt[64 * 64];     // [d][key], XOR-swizzled
  __shared__ __align__(16) ushort Ps[8][16 * 72];  // ping-pong per wave

  bfv8 qf0[2], qf1[2];
#pragma unroll
  for (int f = 0; f < 2; ++f) {
    const ushort* qp = q + base + (size_t)(q0 + f * 16 + fr) * Dc + fq * 8;
    qf0[f] = *reinterpret_cast<const bfv8*>(qp);
    qf1[f] = *reinterpret_cast<const bfv8*>(qp + 32);
  }

  f32x4 oacc[2][4];  // [frag][dtile]
#pragma unroll
  for (int f = 0; f < 2; ++f)
#pragma unroll
    for (int d = 0; d < 4; ++d) oacc[f][d] = f32x4{0.f, 0.f, 0.f, 0.f};
  float mrow[2] = {-3e38f, -3e38f};
  float lrow[2] = {0.f, 0.f};

  const int r8 = tid >> 3;  // 0..31
  const int c8 = tid & 7;   // 16B chunk

  const int sA = (fq ^ (fr & 7)) * 8;        // swizzled read offset, chunks 0-3
  const int sB = ((fq + 4) ^ (fr & 7)) * 8;  // chunks 4-7

  for (int kt = 0; kt < Sc / 64; ++kt) {
    const int key0 = kt * 64;
#pragma unroll
    for (int i = 0; i < 2; ++i) {
      int row = i * 32 + r8;
      int sc = (c8 ^ (row & 7)) * 8;
      cp16(k + base + (size_t)(key0 + row) * Dc + sc, &Ks[i * 2048 + wave * 512]);
      cp16(vt + base + (size_t)row * Sc + key0 + sc, &Vt[i * 2048 + wave * 512]);
    }
    __syncthreads();

    bfv8 kf0[4], kf1[4], vf0[4], vf1[4];
#pragma unroll
    for (int t = 0; t < 4; ++t) {
      int e = (t * 16 + fr) * 64;
      kf0[t] = *reinterpret_cast<const bfv8*>(&Ks[e + sA]);
      kf1[t] = *reinterpret_cast<const bfv8*>(&Ks[e + sB]);
      vf0[t] = *reinterpret_cast<const bfv8*>(&Vt[e + sA]);
      vf1[t] = *reinterpret_cast<const bfv8*>(&Vt[e + sB]);
    }

#pragma unroll
    for (int f = 0; f < 2; ++f) {
      f32x4 sf[4];
      __builtin_amdgcn_s_setprio(1);
#pragma unroll
      for (int t = 0; t < 4; ++t) {
        sf[t] = f32x4{0.f, 0.f, 0.f, 0.f};
        sf[t] = __builtin_amdgcn_mfma_f32_16x16x32_bf16(kf0[t], qf0[f], sf[t], 0, 0, 0);
        sf[t] = __builtin_amdgcn_mfma_f32_16x16x32_bf16(kf1[t], qf1[f], sf[t], 0, 0, 0);
      }
      __builtin_amdgcn_s_setprio(0);
      // lane holds S[q=fr][key = t*16 + fq*4 + r], log2 domain
      float pmax = sf[0][0];
#pragma unroll
      for (int t = 0; t < 4; ++t)
#pragma unroll
        for (int r = 0; r < 4; ++r) pmax = fmaxf(pmax, sf[t][r]);
      float m = mrow[f];
      float mnew = m;
      if (!__all(pmax <= m + 8.f)) {
        float mt = fmaxf(pmax, __shfl_xor(pmax, 16));
        mt = fmaxf(mt, __shfl_xor(mt, 32));
        mnew = fmaxf(m, mt);
        float alpha = exp2f(m - mnew);
        float ar[4];
#pragma unroll
        for (int r = 0; r < 4; ++r) ar[r] = __shfl(alpha, fq * 4 + r);
#pragma unroll
        for (int d = 0; d < 4; ++d)
#pragma unroll
          for (int r = 0; r < 4; ++r) oacc[f][d][r] *= ar[r];
        lrow[f] *= alpha;
        mrow[f] = mnew;
      }
      float p[4][4];
      float rsum = 0.f;
#pragma unroll
      for (int t = 0; t < 4; ++t)
#pragma unroll
        for (int r = 0; r < 4; ++r) {
          p[t][r] = exp2f(sf[t][r] - mnew);
          rsum += p[t][r];
        }
      rsum += __shfl_xor(rsum, 16);
      rsum += __shfl_xor(rsum, 32);
      lrow[f] += rsum;
      ushort* pw = &Ps[wave * 2 + (f & 1)][0];
#pragma unroll
      for (int t = 0; t < 4; ++t) {
        ushort4 pu;
        pu.x = f2bf(p[t][0]);
        pu.y = f2bf(p[t][1]);
        pu.z = f2bf(p[t][2]);
        pu.w = f2bf(p[t][3]);
        *reinterpret_cast<ushort4*>(&pw[fr * 72 + t * 16 + fq * 4]) = pu;
      }
      bfv8 pf0 = *reinterpret_cast<const bfv8*>(&pw[fr * 72 + fq * 8]);
      bfv8 pf1 = *reinterpret_cast<const bfv8*>(&pw[fr * 72 + 32 + fq * 8]);
      __builtin_amdgcn_s_setprio(1);
#pragma unroll
      for (int d = 0; d < 4; ++d) {
        oacc[f][d] = __builtin_amdgcn_mfma_f32_16x16x32_bf16(pf0, vf0[d], oacc[f][d], 0, 0, 0);
        oacc[f][d] = __builtin_amdgcn_mfma_f32_16x16x32_bf16(pf1, vf1[d], oacc[f][d], 0, 0, 0);
      }
      __builtin_amdgcn_s_setprio(0);
    }
    __syncthreads();
  }

  const int b = bh >> 4, h = bh & 15;
#pragma unroll
  for (int f = 0; f < 2; ++f) {
    float linv[4];
#pragma unroll
    for (int r = 0; r < 4; ++r) linv[r] = 1.f / __shfl(lrow[f], fq * 4 + r);
#pragma unroll
    for (int d = 0; d < 4; ++d)
#pragma unroll
      for (int r = 0; r < 4; ++r) {
        int sIdx = q0 + f * 16 + fq * 4 + r;
        o[((size_t)(b * Sc + sIdx)) * Ec + h * 64 + d * 16 + fr] =
            f2bf(oacc[f][d][r] * linv[r]);
      }
  }
}

// -----------------------------------------------------------------------------
extern "C" void kernel_launch(void* const* d_in, const int* in_sizes, int n_in,
                              void* d_out, int out_size, void* d_ws, size_t ws_size,
                              hipStream_t stream) {
  const float* inp = (const float*)d_in[0];
  const float* ln1g = (const float*)d_in[1];
  const float* ln1b = (const float*)d_in[2];
  const float* Wq = (const float*)d_in[3];
  const float* bq = (const float*)d_in[4];
  const float* Wk = (const float*)d_in[5];
  const float* bk = (const float*)d_in[6];
  const float* Wv = (const float*)d_in[7];
  const float* bv = (const float*)d_in[8];
  const float* Wo = (const float*)d_in[9];
  const float* bo = (const float*)d_in[10];
  const float* ln2g = (const float*)d_in[11];
  const float* ln2b = (const float*)d_in[12];
  const float* W1 = (const float*)d_in[13];
  const float* b1 = (const float*)d_in[14];
  const float* W2 = (const float*)d_in[15];
  const float* b2 = (const float*)d_in[16];

  char* wsb = (char*)d_ws;
  size_t off = 0;
  auto alloc = [&](size_t bytes) {
    char* p = wsb + off;
    off += (bytes + 255) & ~(size_t)255;
    return p;
  };
  float* xf = (float*)alloc((size_t)Mc * Ec * 4);
  ushort* xb = (ushort*)alloc((size_t)Mc * Ec * 2);
  ushort* qbuf = (ushort*)alloc((size_t)Mc * Ec * 2);
  ushort* kbuf = (ushort*)alloc((size_t)Mc * Ec * 2);
  ushort* vtbuf = (ushort*)alloc((size_t)Mc * Ec * 2);
  ushort* abuf = (ushort*)alloc((size_t)Mc * Ec * 2);
  ushort* h1 = (ushort*)alloc((size_t)Mc * 2 * Ec * 2);
  ushort* WqkvT = (ushort*)alloc((size_t)3 * Ec * Ec * 2);  // [3E][E]
  ushort* WoT = (ushort*)alloc((size_t)Ec * Ec * 2);
  ushort* W1T = (ushort*)alloc((size_t)Ec * 2 * Ec * 2);
  ushort* W2T = (ushort*)alloc((size_t)Ec * 2 * Ec * 2);
  (void)in_sizes; (void)n_in; (void)out_size; (void)ws_size;

  dim3 tb(32, 8);
  wcvt_kernel<<<dim3(Ec / 32, Ec / 32), tb, 0, stream>>>(Wq, WqkvT, Ec, Ec);
  wcvt_kernel<<<dim3(Ec / 32, Ec / 32), tb, 0, stream>>>(Wk, WqkvT + (size_t)Ec * Ec, Ec, Ec);
  wcvt_kernel<<<dim3(Ec / 32, Ec / 32), tb, 0, stream>>>(Wv, WqkvT + (size_t)2 * Ec * Ec, Ec, Ec);
  wcvt_kernel<<<dim3(Ec / 32, Ec / 32), tb, 0, stream>>>(Wo, WoT, Ec, Ec);
  wcvt_kernel<<<dim3(Ec / 32, 2 * Ec / 32), tb, 0, stream>>>(W1, W1T, Ec, 2 * Ec);
  wcvt_kernel<<<dim3(2 * Ec / 32, Ec / 32), tb, 0, stream>>>(W2, W2T, 2 * Ec, Ec);

  ln_kernel<<<Mc, 256, 0, stream>>>(inp, ln1g, ln1b, xf, xb);

  // Fused QKV: N=3072. Q pre-scale (1/sqrt(D))*log2(e) -> exp2-domain softmax
  gemm_kernel<0><<<dim3(3 * Ec / 128, Mc / 128), 256, 0, stream>>>(
      Mc, 3 * Ec, Ec, xb, WqkvT, bq, bk, bv, nullptr, nullptr, qbuf, kbuf,
      vtbuf, 0.18033688f);

  attn_kernel<<<Bc * Hc * (Sc / 128), 256, 0, stream>>>(qbuf, kbuf, vtbuf, abuf);

  gemm_kernel<1><<<dim3(Ec / 128, Mc / 128), 256, 0, stream>>>(
      Mc, Ec, Ec, abuf, WoT, bo, nullptr, nullptr, xf, xf, nullptr, nullptr,
      nullptr, 1.f);

  ln_kernel<<<Mc, 256, 0, stream>>>(xf, ln2g, ln2b, xf, xb);

  gemm_kernel<2><<<dim3(2 * Ec / 128, Mc / 128), 256, 0, stream>>>(
      Mc, 2 * Ec, Ec, xb, W1T, b1, nullptr, nullptr, nullptr, nullptr, h1,
      nullptr, nullptr, 1.f);

  gemm_kernel<1><<<dim3(Ec / 128, Mc / 128), 256, 0, stream>>>(
      Mc, Ec, 2 * Ec, h1, W2T, b2, nullptr, nullptr, xf, (float*)d_out,
      nullptr, nullptr, nullptr, 1.f);
}

// Round 6
// 415.566 us; speedup vs baseline: 1.2042x; 1.0029x over previous
//
#include <hip/hip_runtime.h>
#include <hip/hip_bf16.h>

typedef float f32x4 __attribute__((ext_vector_type(4)));
typedef __bf16 bfv8 __attribute__((ext_vector_type(8)));

constexpr int Bc = 4, Sc = 2048, Ec = 1024, Hc = 16, Dc = 64;
constexpr int Mc = Bc * Sc;  // 8192 rows

// HW packed f32->bf16 RNE convert (no builtin on gfx950; inline asm per guide)
__device__ __forceinline__ uint pkbf(float lo, float hi) {
  uint r;
  asm("v_cvt_pk_bf16_f32 %0, %1, %2" : "=v"(r) : "v"(lo), "v"(hi));
  return r;
}
__device__ __forceinline__ ushort f2bf(float f) {
  return (ushort)pkbf(f, 0.f);
}

typedef __attribute__((address_space(1))) unsigned int as1_u32;
typedef __attribute__((address_space(3))) unsigned int as3_u32;
__device__ __forceinline__ void cp16(const ushort* g, ushort* l) {
  // async global->LDS, 16B per lane; LDS dest = wave-uniform base + lane*16
  __builtin_amdgcn_global_load_lds((as1_u32*)g, (as3_u32*)l, 16, 0, 0);
}

// ---------------- weight convert + transpose: W[K][N] f32 -> WT[N][K] bf16 ----
__global__ __launch_bounds__(256) void wcvt_kernel(const float* __restrict__ W,
                                                   ushort* __restrict__ WT,
                                                   int K, int N) {
  __shared__ float t[32][33];
  int k0 = blockIdx.x * 32, n0 = blockIdx.y * 32;
  int tx = threadIdx.x, ty = threadIdx.y;  // (32,8)
#pragma unroll
  for (int i = 0; i < 32; i += 8)
    t[ty + i][tx] = W[(size_t)(k0 + ty + i) * N + n0 + tx];
  __syncthreads();
#pragma unroll
  for (int i = 0; i < 32; i += 8)
    WT[(size_t)(n0 + ty + i) * K + k0 + tx] = f2bf(t[tx][ty + i]);
}

// ---------------- LayerNorm: row of 1024, one block per row ------------------
__global__ __launch_bounds__(256) void ln_kernel(const float* in,
                                                 const float* __restrict__ g,
                                                 const float* __restrict__ bb,
                                                 float* of, ushort* ob) {
  int row = blockIdx.x;
  int t = threadIdx.x;
  float4 x = reinterpret_cast<const float4*>(in + (size_t)row * Ec)[t];
  float s = x.x + x.y + x.z + x.w;
  float q = x.x * x.x + x.y * x.y + x.z * x.z + x.w * x.w;
#pragma unroll
  for (int o = 32; o > 0; o >>= 1) {
    s += __shfl_down(s, o);
    q += __shfl_down(q, o);
  }
  __shared__ float red[10];
  int wv = t >> 6;
  if ((t & 63) == 0) { red[wv] = s; red[4 + wv] = q; }
  __syncthreads();
  if (t == 0) {
    float S = red[0] + red[1] + red[2] + red[3];
    float Q = red[4] + red[5] + red[6] + red[7];
    float mu = S * (1.f / Ec);
    float var = Q * (1.f / Ec) - mu * mu;
    red[8] = mu;
    red[9] = rsqrtf(var + 1e-5f);
  }
  __syncthreads();
  float mu = red[8], rs = red[9];
  float4 gg = reinterpret_cast<const float4*>(g)[t];
  float4 b4 = reinterpret_cast<const float4*>(bb)[t];
  float4 y;
  y.x = (x.x - mu) * rs * gg.x + b4.x;
  y.y = (x.y - mu) * rs * gg.y + b4.y;
  y.z = (x.z - mu) * rs * gg.z + b4.z;
  y.w = (x.w - mu) * rs * gg.w + b4.w;
  reinterpret_cast<float4*>(of + (size_t)row * Ec)[t] = y;
  uint2 u;
  u.x = pkbf(y.x, y.y);
  u.y = pkbf(y.z, y.w);
  reinterpret_cast<uint2*>(ob + (size_t)row * Ec)[t] = u;
}

// ---------------- GEMM: C[M,N] = A[M,K](bf16) * BT[N,K]^T(bf16) + epilogue ---
// 128x128 tile, BK=64, LDS double-buffered (64KB, 2 blocks/CU), counted
// vmcnt(8) + raw s_barrier so next tile's global_load_lds stays in flight
// across the barrier. LDS XOR-swizzled (col ^= (row&3)<<4) via pre-swizzled
// global source; frag ds_read_b128 at the 8-cy wave64 floor.
// MODE 0: fused QKV, N=3Ec; region 0 -> Q*qscale [B,H,S,D], 1 -> K [B,H,S,D],
//         2 -> V^T [B,H,D,S] packed
// MODE 1: f32 out = acc + bias + resid (row-major)
// MODE 2: bf16 out = gelu(acc + bias) (row-major)
template <int MODE>
__global__ __launch_bounds__(256, 2) void gemm_kernel(
    int M, int N, int K, const ushort* __restrict__ A,
    const ushort* __restrict__ BT, const float* __restrict__ b0,
    const float* __restrict__ b1, const float* __restrict__ b2,
    const float* resid, float* outF, ushort* o0, ushort* o1, ushort* o2,
    float qscale) {
  __shared__ __align__(16) ushort As[2][128 * 64];
  __shared__ __align__(16) ushort Bs[2][128 * 64];
  const int tid = threadIdx.x;
  const int lane = tid & 63, wave = tid >> 6;
  const int wr = wave >> 1, wc = wave & 1;
  const int fr = lane & 15, fq = lane >> 4;
  // XCD-chunked swizzle (nwg % 8 == 0 for all launches)
  const int nx = gridDim.x;
  int flat = blockIdx.x + nx * blockIdx.y;
  int cpx = (nx * gridDim.y) >> 3;
  int work = (flat & 7) * cpx + (flat >> 3);
  const int n0 = (work % nx) * 128, m0 = (work / nx) * 128;

  f32x4 acc[4][4];
#pragma unroll
  for (int i = 0; i < 4; i++)
#pragma unroll
    for (int j = 0; j < 4; j++) acc[i][j] = f32x4{0.f, 0.f, 0.f, 0.f};

  const int srow = tid >> 3;   // 0..31 (+32 per chunk)
  const int sslot = tid & 7;   // 16B slot within 128B row

  auto STAGE = [&](int p, int k0) {
#pragma unroll
    for (int c = 0; c < 4; ++c) {
      int row = c * 32 + srow;
      int scol = (sslot ^ (2 * (row & 3))) * 8;  // inverse-swizzled source
      cp16(A + (size_t)(m0 + row) * K + k0 + scol,
           &As[p][(c * 256 + wave * 64) * 8]);
      cp16(BT + (size_t)(n0 + row) * K + k0 + scol,
           &Bs[p][(c * 256 + wave * 64) * 8]);
    }
  };

  STAGE(0, 0);
  const int nt = K >> 6;
  for (int kt = 0; kt < nt; ++kt) {
    const int p = kt & 1;
    if (kt + 1 < nt) {
      STAGE(p ^ 1, (kt + 1) << 6);
      asm volatile("s_waitcnt vmcnt(8)" ::: "memory");  // tile kt landed
    } else {
      asm volatile("s_waitcnt vmcnt(0)" ::: "memory");
    }
    __builtin_amdgcn_s_barrier();
#pragma unroll
    for (int kk = 0; kk < 2; ++kk) {
      bfv8 af[4], bf[4];
#pragma unroll
      for (int m = 0; m < 4; m++) {
        int row = wr * 64 + m * 16 + fr;
        af[m] = *reinterpret_cast<const bfv8*>(
            &As[p][row * 64 + ((kk * 32 + fq * 8) ^ ((fr & 3) << 4))]);
      }
#pragma unroll
      for (int n = 0; n < 4; n++) {
        int row = wc * 64 + n * 16 + fr;
        bf[n] = *reinterpret_cast<const bfv8*>(
            &Bs[p][row * 64 + ((kk * 32 + fq * 8) ^ ((fr & 3) << 4))]);
      }
      __builtin_amdgcn_s_setprio(1);
#pragma unroll
      for (int m = 0; m < 4; m++)
#pragma unroll
        for (int n = 0; n < 4; n++)
          acc[m][n] =
              __builtin_amdgcn_mfma_f32_16x16x32_bf16(af[m], bf[n], acc[m][n], 0, 0, 0);
      __builtin_amdgcn_s_setprio(0);
    }
    __builtin_amdgcn_sched_barrier(0);
    __builtin_amdgcn_s_barrier();
  }

#pragma unroll
  for (int m = 0; m < 4; m++) {
#pragma unroll
    for (int n = 0; n < 4; n++) {
      const int row0 = m0 + wr * 64 + m * 16 + fq * 4;
      const int col = n0 + wc * 64 + n * 16 + fr;
      if constexpr (MODE == 0) {
        const int region = col >> 10, c1 = col & (Ec - 1);
        const int b = row0 >> 11, s0 = row0 & (Sc - 1);
        const int h = c1 >> 6, d = c1 & (Dc - 1);
        const float bb = (region == 0 ? b0 : region == 1 ? b1 : b2)[c1];
        if (region == 2) {
          uint2 u;
          u.x = pkbf(acc[m][n][0] + bb, acc[m][n][1] + bb);
          u.y = pkbf(acc[m][n][2] + bb, acc[m][n][3] + bb);
          *reinterpret_cast<uint2*>(
              &o2[(((size_t)b * Hc + h) * Dc + d) * Sc + s0]) = u;
        } else {
          ushort* dst = region ? o1 : o0;
          const float sc = region ? 1.f : qscale;
#pragma unroll
          for (int r = 0; r < 4; r++)
            dst[(((size_t)b * Hc + h) * Sc + s0 + r) * Dc + d] =
                f2bf((acc[m][n][r] + bb) * sc);
        }
      } else {
        const float bb = b0[col];
#pragma unroll
        for (int r = 0; r < 4; r++) {
          int row = row0 + r;
          float vacc = acc[m][n][r] + bb;
          if constexpr (MODE == 1) {
            size_t idx = (size_t)row * N + col;
            outF[idx] = vacc + resid[idx];
          } else {
            vacc = 0.5f * vacc * (1.f + erff(vacc * 0.70710678118f));
            o0[(size_t)row * N + col] = f2bf(vacc);
          }
        }
      }
    }
  }
}

// ---------------- Flash attention (32 q-rows per wave, 128 per block) --------
// q,k: [B,H,S,D] bf16 (q pre-scaled by log2e/sqrt(D)); vt: [B,H,D,S] bf16.
// Swapped QK^T; softmax in exp2 domain; defer-max (THR=8, log2 units).
// K/V LDS XOR-swizzled, staged via pre-swizzled-source global_load_lds;
// K,V fragments hoisted to registers, reused by 2 q-frags.
// P pack via v_cvt_pk_bf16_f32 (HW RNE, 1 inst / 2 elems).
__global__ __launch_bounds__(256) void attn_kernel(const ushort* __restrict__ q,
                                                   const ushort* __restrict__ k,
                                                   const ushort* __restrict__ vt,
                                                   ushort* __restrict__ o) {
  int flat = blockIdx.x;                     // 1024 blocks
  int swz = (flat & 7) * 128 + (flat >> 3);  // XCD-chunked: 8 heads per XCD
  const int qb = swz & 15;                   // 16 q-blocks of 128 rows
  const int bh = swz >> 4;
  const int tid = threadIdx.x, lane = tid & 63, wave = tid >> 6;
  const int fr = lane & 15, fq = lane >> 4;
  const size_t base = (size_t)bh * Sc * Dc;
  const int q0 = qb * 128 + wave * 32;

  __shared__ __align__(16) ushort Ks[64 * 64];     // [key][d], XOR-swizzled
  __shared__ __align__(16) ushort Vt[64 * 64];     // [d][key], XOR-swizzled
  __shared__ __align__(16) ushort Ps[8][16 * 72];  // ping-pong per wave

  bfv8 qf0[2], qf1[2];
#pragma unroll
  for (int f = 0; f < 2; ++f) {
    const ushort* qp = q + base + (size_t)(q0 + f * 16 + fr) * Dc + fq * 8;
    qf0[f] = *reinterpret_cast<const bfv8*>(qp);
    qf1[f] = *reinterpret_cast<const bfv8*>(qp + 32);
  }

  f32x4 oacc[2][4];  // [frag][dtile]
#pragma unroll
  for (int f = 0; f < 2; ++f)
#pragma unroll
    for (int d = 0; d < 4; ++d) oacc[f][d] = f32x4{0.f, 0.f, 0.f, 0.f};
  float mrow[2] = {-3e38f, -3e38f};
  float lrow[2] = {0.f, 0.f};

  const int r8 = tid >> 3;  // 0..31
  const int c8 = tid & 7;   // 16B chunk

  const int sA = (fq ^ (fr & 7)) * 8;        // swizzled read offset, chunks 0-3
  const int sB = ((fq + 4) ^ (fr & 7)) * 8;  // chunks 4-7

  for (int kt = 0; kt < Sc / 64; ++kt) {
    const int key0 = kt * 64;
#pragma unroll
    for (int i = 0; i < 2; ++i) {
      int row = i * 32 + r8;
      int sc = (c8 ^ (row & 7)) * 8;
      cp16(k + base + (size_t)(key0 + row) * Dc + sc, &Ks[i * 2048 + wave * 512]);
      cp16(vt + base + (size_t)row * Sc + key0 + sc, &Vt[i * 2048 + wave * 512]);
    }
    __syncthreads();

    bfv8 kf0[4], kf1[4], vf0[4], vf1[4];
#pragma unroll
    for (int t = 0; t < 4; ++t) {
      int e = (t * 16 + fr) * 64;
      kf0[t] = *reinterpret_cast<const bfv8*>(&Ks[e + sA]);
      kf1[t] = *reinterpret_cast<const bfv8*>(&Ks[e + sB]);
      vf0[t] = *reinterpret_cast<const bfv8*>(&Vt[e + sA]);
      vf1[t] = *reinterpret_cast<const bfv8*>(&Vt[e + sB]);
    }

#pragma unroll
    for (int f = 0; f < 2; ++f) {
      f32x4 sf[4];
      __builtin_amdgcn_s_setprio(1);
#pragma unroll
      for (int t = 0; t < 4; ++t) {
        sf[t] = f32x4{0.f, 0.f, 0.f, 0.f};
        sf[t] = __builtin_amdgcn_mfma_f32_16x16x32_bf16(kf0[t], qf0[f], sf[t], 0, 0, 0);
        sf[t] = __builtin_amdgcn_mfma_f32_16x16x32_bf16(kf1[t], qf1[f], sf[t], 0, 0, 0);
      }
      __builtin_amdgcn_s_setprio(0);
      // lane holds S[q=fr][key = t*16 + fq*4 + r], log2 domain
      float pmax = sf[0][0];
#pragma unroll
      for (int t = 0; t < 4; ++t)
#pragma unroll
        for (int r = 0; r < 4; ++r) pmax = fmaxf(pmax, sf[t][r]);
      float m = mrow[f];
      float mnew = m;
      if (!__all(pmax <= m + 8.f)) {
        float mt = fmaxf(pmax, __shfl_xor(pmax, 16));
        mt = fmaxf(mt, __shfl_xor(mt, 32));
        mnew = fmaxf(m, mt);
        float alpha = exp2f(m - mnew);
        float ar[4];
#pragma unroll
        for (int r = 0; r < 4; ++r) ar[r] = __shfl(alpha, fq * 4 + r);
#pragma unroll
        for (int d = 0; d < 4; ++d)
#pragma unroll
          for (int r = 0; r < 4; ++r) oacc[f][d][r] *= ar[r];
        lrow[f] *= alpha;
        mrow[f] = mnew;
      }
      float p[4][4];
      float rsum = 0.f;
#pragma unroll
      for (int t = 0; t < 4; ++t)
#pragma unroll
        for (int r = 0; r < 4; ++r) {
          p[t][r] = exp2f(sf[t][r] - mnew);
          rsum += p[t][r];
        }
      rsum += __shfl_xor(rsum, 16);
      rsum += __shfl_xor(rsum, 32);
      lrow[f] += rsum;
      ushort* pw = &Ps[wave * 2 + (f & 1)][0];
#pragma unroll
      for (int t = 0; t < 4; ++t) {
        uint2 pu;
        pu.x = pkbf(p[t][0], p[t][1]);
        pu.y = pkbf(p[t][2], p[t][3]);
        *reinterpret_cast<uint2*>(&pw[fr * 72 + t * 16 + fq * 4]) = pu;
      }
      bfv8 pf0 = *reinterpret_cast<const bfv8*>(&pw[fr * 72 + fq * 8]);
      bfv8 pf1 = *reinterpret_cast<const bfv8*>(&pw[fr * 72 + 32 + fq * 8]);
      __builtin_amdgcn_s_setprio(1);
#pragma unroll
      for (int d = 0; d < 4; ++d) {
        oacc[f][d] = __builtin_amdgcn_mfma_f32_16x16x32_bf16(pf0, vf0[d], oacc[f][d], 0, 0, 0);
        oacc[f][d] = __builtin_amdgcn_mfma_f32_16x16x32_bf16(pf1, vf1[d], oacc[f][d], 0, 0, 0);
      }
      __builtin_amdgcn_s_setprio(0);
    }
    __syncthreads();
  }

  const int b = bh >> 4, h = bh & 15;
#pragma unroll
  for (int f = 0; f < 2; ++f) {
    float linv[4];
#pragma unroll
    for (int r = 0; r < 4; ++r) linv[r] = 1.f / __shfl(lrow[f], fq * 4 + r);
#pragma unroll
    for (int d = 0; d < 4; ++d)
#pragma unroll
      for (int r = 0; r < 4; ++r) {
        int sIdx = q0 + f * 16 + fq * 4 + r;
        o[((size_t)(b * Sc + sIdx)) * Ec + h * 64 + d * 16 + fr] =
            f2bf(oacc[f][d][r] * linv[r]);
      }
  }
}

// -----------------------------------------------------------------------------
extern "C" void kernel_launch(void* const* d_in, const int* in_sizes, int n_in,
                              void* d_out, int out_size, void* d_ws, size_t ws_size,
                              hipStream_t stream) {
  const float* inp = (const float*)d_in[0];
  const float* ln1g = (const float*)d_in[1];
  const float* ln1b = (const float*)d_in[2];
  const float* Wq = (const float*)d_in[3];
  const float* bq = (const float*)d_in[4];
  const float* Wk = (const float*)d_in[5];
  const float* bk = (const float*)d_in[6];
  const float* Wv = (const float*)d_in[7];
  const float* bv = (const float*)d_in[8];
  const float* Wo = (const float*)d_in[9];
  const float* bo = (const float*)d_in[10];
  const float* ln2g = (const float*)d_in[11];
  const float* ln2b = (const float*)d_in[12];
  const float* W1 = (const float*)d_in[13];
  const float* b1 = (const float*)d_in[14];
  const float* W2 = (const float*)d_in[15];
  const float* b2 = (const float*)d_in[16];

  char* wsb = (char*)d_ws;
  size_t off = 0;
  auto alloc = [&](size_t bytes) {
    char* p = wsb + off;
    off += (bytes + 255) & ~(size_t)255;
    return p;
  };
  float* xf = (float*)alloc((size_t)Mc * Ec * 4);
  ushort* xb = (ushort*)alloc((size_t)Mc * Ec * 2);
  ushort* qbuf = (ushort*)alloc((size_t)Mc * Ec * 2);
  ushort* kbuf = (ushort*)alloc((size_t)Mc * Ec * 2);
  ushort* vtbuf = (ushort*)alloc((size_t)Mc * Ec * 2);
  ushort* abuf = (ushort*)alloc((size_t)Mc * Ec * 2);
  ushort* h1 = (ushort*)alloc((size_t)Mc * 2 * Ec * 2);
  ushort* WqkvT = (ushort*)alloc((size_t)3 * Ec * Ec * 2);  // [3E][E]
  ushort* WoT = (ushort*)alloc((size_t)Ec * Ec * 2);
  ushort* W1T = (ushort*)alloc((size_t)Ec * 2 * Ec * 2);
  ushort* W2T = (ushort*)alloc((size_t)Ec * 2 * Ec * 2);
  (void)in_sizes; (void)n_in; (void)out_size; (void)ws_size;

  dim3 tb(32, 8);
  wcvt_kernel<<<dim3(Ec / 32, Ec / 32), tb, 0, stream>>>(Wq, WqkvT, Ec, Ec);
  wcvt_kernel<<<dim3(Ec / 32, Ec / 32), tb, 0, stream>>>(Wk, WqkvT + (size_t)Ec * Ec, Ec, Ec);
  wcvt_kernel<<<dim3(Ec / 32, Ec / 32), tb, 0, stream>>>(Wv, WqkvT + (size_t)2 * Ec * Ec, Ec, Ec);
  wcvt_kernel<<<dim3(Ec / 32, Ec / 32), tb, 0, stream>>>(Wo, WoT, Ec, Ec);
  wcvt_kernel<<<dim3(Ec / 32, 2 * Ec / 32), tb, 0, stream>>>(W1, W1T, Ec, 2 * Ec);
  wcvt_kernel<<<dim3(2 * Ec / 32, Ec / 32), tb, 0, stream>>>(W2, W2T, 2 * Ec, Ec);

  ln_kernel<<<Mc, 256, 0, stream>>>(inp, ln1g, ln1b, xf, xb);

  // Fused QKV: N=3072. Q pre-scale (1/sqrt(D))*log2(e) -> exp2-domain softmax
  gemm_kernel<0><<<dim3(3 * Ec / 128, Mc / 128), 256, 0, stream>>>(
      Mc, 3 * Ec, Ec, xb, WqkvT, bq, bk, bv, nullptr, nullptr, qbuf, kbuf,
      vtbuf, 0.18033688f);

  attn_kernel<<<Bc * Hc * (Sc / 128), 256, 0, stream>>>(qbuf, kbuf, vtbuf, abuf);

  gemm_kernel<1><<<dim3(Ec / 128, Mc / 128), 256, 0, stream>>>(
      Mc, Ec, Ec, abuf, WoT, bo, nullptr, nullptr, xf, xf, nullptr, nullptr,
      nullptr, 1.f);

  ln_kernel<<<Mc, 256, 0, stream>>>(xf, ln2g, ln2b, xf, xb);

  gemm_kernel<2><<<dim3(2 * Ec / 128, Mc / 128), 256, 0, stream>>>(
      Mc, 2 * Ec, Ec, xb, W1T, b1, nullptr, nullptr, nullptr, nullptr, h1,
      nullptr, nullptr, 1.f);

  gemm_kernel<1><<<dim3(Ec / 128, Mc / 128), 256, 0, stream>>>(
      Mc, Ec, 2 * Ec, h1, W2T, b2, nullptr, nullptr, xf, (float*)d_out,
      nullptr, nullptr, nullptr, 1.f);
}